// Round 1
// baseline (1452.729 us; speedup 1.0000x reference)
//
#include <hip/hip_runtime.h>
#include <math.h>

#define BB 512
#define SS 100
#define HH 768

// ---------------- K0: d_rep[b,h] = mean_s X[b,s,h] ----------------
__global__ __launch_bounds__(256) void k_drep(const float* __restrict__ X,
                                              float* __restrict__ drep) {
    int b = blockIdx.x;
    const float* xb = X + (size_t)b * SS * HH;
    for (int h = threadIdx.x; h < HH; h += 256) {
        float s = 0.f;
        #pragma unroll 4
        for (int i = 0; i < SS; ++i) s += xb[(size_t)i * HH + h];
        drep[(size_t)b * HH + h] = s * (1.0f / SS);
    }
}

// ---------------- K1: C[m,n] = sum_k A[m,k]*Bm[n,k]  (NT, 64x64x16) ----------------
// used for t = d_rep @ W_rel^T  (M=512, N=768, K=768; all divisible, no guards)
__global__ __launch_bounds__(256) void k_gemm_nt(const float* __restrict__ A,
                                                 const float* __restrict__ Bm,
                                                 float* __restrict__ C,
                                                 int N, int K) {
    __shared__ float As[64 * 20];
    __shared__ float Bs[64 * 20];
    int tid = threadIdx.x;
    int ty = tid >> 4, tx = tid & 15;
    int m0 = blockIdx.y * 64, n0 = blockIdx.x * 64;
    int lr = tid >> 2, lc = (tid & 3) * 4;
    float acc[4][4] = {};
    for (int kt = 0; kt < K; kt += 16) {
        *(float4*)(As + lr * 20 + lc) = *(const float4*)(A + (size_t)(m0 + lr) * K + kt + lc);
        *(float4*)(Bs + lr * 20 + lc) = *(const float4*)(Bm + (size_t)(n0 + lr) * K + kt + lc);
        __syncthreads();
        #pragma unroll
        for (int k = 0; k < 16; k += 2) {
            float2 ar[4], br[4];
            #pragma unroll
            for (int ii = 0; ii < 4; ++ii) ar[ii] = *(const float2*)(As + (ty + 16 * ii) * 20 + k);
            #pragma unroll
            for (int jj = 0; jj < 4; ++jj) br[jj] = *(const float2*)(Bs + (tx + 16 * jj) * 20 + k);
            #pragma unroll
            for (int ii = 0; ii < 4; ++ii)
                #pragma unroll
                for (int jj = 0; jj < 4; ++jj)
                    acc[ii][jj] = fmaf(ar[ii].y, br[jj].y, fmaf(ar[ii].x, br[jj].x, acc[ii][jj]));
        }
        __syncthreads();
    }
    #pragma unroll
    for (int ii = 0; ii < 4; ++ii)
        #pragma unroll
        for (int jj = 0; jj < 4; ++jj)
            C[(size_t)(m0 + ty + 16 * ii) * N + n0 + tx + 16 * jj] = acc[ii][jj];
}

// ---------------- K2: a[b,i] = X[b,i]·(Wc + t[b]) + b00  (cont + rel fused) ----------------
__global__ __launch_bounds__(256) void k_contrel(const float* __restrict__ X,
                                                 const float* __restrict__ Wc,
                                                 const float* __restrict__ tmat,
                                                 const float* __restrict__ bmat,
                                                 float* __restrict__ avec) {
    __shared__ float u[HH];
    int b = blockIdx.x;
    for (int h = threadIdx.x; h < HH; h += 256)
        u[h] = Wc[h] + tmat[(size_t)b * HH + h];
    __syncthreads();
    int wave = threadIdx.x >> 6, lane = threadIdx.x & 63;
    float b00 = bmat[0];
    for (int r = wave; r < SS; r += 4) {
        const float* xr = X + ((size_t)b * SS + r) * HH;
        float s = 0.f;
        for (int h = lane; h < HH; h += 64) s = fmaf(xr[h], u[h], s);
        #pragma unroll
        for (int off = 32; off > 0; off >>= 1) s += __shfl_down(s, off);
        if (lane == 0) avec[(size_t)b * SS + r] = s + b00;
    }
}

// ---------------- K3: GEMM1  Y = A @ W  (NN, 128x64x16, TM=8 TN=4) ----------------
__global__ __launch_bounds__(256) void k_gemm1(const float* __restrict__ A,
                                               const float* __restrict__ W,
                                               float* __restrict__ Y) {
    __shared__ float As[128 * 20];
    __shared__ float Bs[16 * 68];
    int tid = threadIdx.x;
    int ty = tid >> 4, tx = tid & 15;
    size_t m0 = (size_t)blockIdx.y * 128;
    int n0 = blockIdx.x * 64;
    int lr = tid >> 2, lc = (tid & 3) * 4;
    int br_ = tid >> 4, bc = (tid & 15) * 4;
    float acc[8][4] = {};
    for (int kt = 0; kt < HH; kt += 16) {
        *(float4*)(As + lr * 20 + lc)        = *(const float4*)(A + (m0 + lr) * HH + kt + lc);
        *(float4*)(As + (lr + 64) * 20 + lc) = *(const float4*)(A + (m0 + lr + 64) * HH + kt + lc);
        *(float4*)(Bs + br_ * 68 + bc)       = *(const float4*)(W + (size_t)(kt + br_) * HH + n0 + bc);
        __syncthreads();
        #pragma unroll
        for (int k = 0; k < 16; k += 2) {
            float2 ar[8]; float b0[4], b1[4];
            #pragma unroll
            for (int ii = 0; ii < 8; ++ii) ar[ii] = *(const float2*)(As + (ty + 16 * ii) * 20 + k);
            #pragma unroll
            for (int jj = 0; jj < 4; ++jj) {
                b0[jj] = Bs[k * 68 + tx + 16 * jj];
                b1[jj] = Bs[(k + 1) * 68 + tx + 16 * jj];
            }
            #pragma unroll
            for (int ii = 0; ii < 8; ++ii)
                #pragma unroll
                for (int jj = 0; jj < 4; ++jj)
                    acc[ii][jj] = fmaf(ar[ii].y, b1[jj], fmaf(ar[ii].x, b0[jj], acc[ii][jj]));
        }
        __syncthreads();
    }
    #pragma unroll
    for (int ii = 0; ii < 8; ++ii) {
        size_t row = m0 + ty + 16 * ii;
        #pragma unroll
        for (int jj = 0; jj < 4; ++jj)
            Y[row * HH + n0 + tx + 16 * jj] = acc[ii][jj];
    }
}

// ---------------- K4: GEMM2  q[b] = sigmoid(Y[b] @ X[b]^T + a[b,i])  (one block/batch) ----------------
__global__ __launch_bounds__(256) void k_gemm2(const float* __restrict__ Ybuf,
                                               const float* __restrict__ X,
                                               const float* __restrict__ avec,
                                               float* __restrict__ q,
                                               int b_off) {
    __shared__ float As[112 * 36];  // rows 100..111 uninitialized; never stored (guarded)
    __shared__ float Bs[112 * 36];
    int bl = blockIdx.x;
    int b = b_off + bl;
    const float* Ab = Ybuf + (size_t)bl * SS * HH;
    const float* Bb = X + (size_t)b * SS * HH;
    int tid = threadIdx.x;
    int ty = tid >> 4, tx = tid & 15;
    float acc[7][7] = {};
    for (int kt = 0; kt < HH; kt += 32) {
        for (int t2 = tid; t2 < 800; t2 += 256) {  // 100 rows x 8 float4
            int r = t2 >> 3, c = (t2 & 7) * 4;
            *(float4*)(As + r * 36 + c) = *(const float4*)(Ab + (size_t)r * HH + kt + c);
            *(float4*)(Bs + r * 36 + c) = *(const float4*)(Bb + (size_t)r * HH + kt + c);
        }
        __syncthreads();
        #pragma unroll 4
        for (int k = 0; k < 32; k += 2) {
            float2 ar[7], br[7];
            #pragma unroll
            for (int ii = 0; ii < 7; ++ii) ar[ii] = *(const float2*)(As + (ty + 16 * ii) * 36 + k);
            #pragma unroll
            for (int jj = 0; jj < 7; ++jj) br[jj] = *(const float2*)(Bs + (tx + 16 * jj) * 36 + k);
            #pragma unroll
            for (int ii = 0; ii < 7; ++ii)
                #pragma unroll
                for (int jj = 0; jj < 7; ++jj)
                    acc[ii][jj] = fmaf(ar[ii].y, br[jj].y, fmaf(ar[ii].x, br[jj].x, acc[ii][jj]));
        }
        __syncthreads();
    }
    #pragma unroll
    for (int ii = 0; ii < 7; ++ii) {
        int i = ty + 16 * ii;
        if (i >= SS) continue;
        float arow = avec[(size_t)b * SS + i];
        #pragma unroll
        for (int jj = 0; jj < 7; ++jj) {
            int j = tx + 16 * jj;
            if (j >= SS) continue;
            float v = acc[ii][jj] + arow;
            q[(size_t)b * SS * SS + (size_t)i * SS + j] = 1.0f / (1.0f + __expf(-v));
        }
    }
}

// ---------------- K5: colsum + fixed-point solve, one block per batch ----------------
// x = 0.2*y + 0.8*qD*x contracts at 0.8/iter in 1-norm (qD column-stochastic).
// 64 iters -> error <= 2*0.8^64 ~ 1.3e-6, well under the 2.93e-4 threshold.
__global__ __launch_bounds__(128) void k_solve(const float* __restrict__ q,
                                               float* __restrict__ out) {
    __shared__ float m[SS * 101];  // pitch 101: stride-101 matvec reads are conflict-free
    __shared__ float cs[SS];
    __shared__ float x0[SS], x1[SS];
    int b = blockIdx.x, tid = threadIdx.x;
    const float* qb = q + (size_t)b * SS * SS;
    for (int e4 = tid; e4 < SS * SS / 4; e4 += 128) {
        float4 v = *(const float4*)(qb + (size_t)e4 * 4);
        int e = e4 * 4, r = e / 100, c = e - r * 100;  // 4*e4 % 100 <= 96, never crosses a row
        m[r * 101 + c]     = v.x;
        m[r * 101 + c + 1] = v.y;
        m[r * 101 + c + 2] = v.z;
        m[r * 101 + c + 3] = v.w;
    }
    __syncthreads();
    if (tid < SS) {
        float s = 0.f;
        for (int i = 0; i < SS; ++i) s += m[i * 101 + tid];
        cs[tid] = 0.8f / s;
    }
    __syncthreads();
    if (tid < SS) {
        float f = cs[tid];
        for (int i = 0; i < SS; ++i) m[i * 101 + tid] *= f;   // m := lamb * q D^-1
        x0[tid] = 1.0f / SS;
    }
    __syncthreads();
    float* xa = x0; float* xb = x1;
    for (int it = 0; it < 64; ++it) {
        if (tid < SS) {
            float s = 0.002f;  // (1-lamb)/S
            #pragma unroll 4
            for (int j = 0; j < SS; ++j) s = fmaf(m[tid * 101 + j], xa[j], s);
            xb[tid] = s;
        }
        __syncthreads();
        float* tmp = xa; xa = xb; xb = tmp;
    }
    if (tid < SS) out[(size_t)b * SS + tid] = xa[tid];
}

extern "C" void kernel_launch(void* const* d_in, const int* in_sizes, int n_in,
                              void* d_out, int out_size, void* d_ws, size_t ws_size,
                              hipStream_t stream) {
    (void)in_sizes; (void)n_in; (void)out_size;
    const float* X    = (const float*)d_in[0];
    // d_in[1] = mask_cls: all ones per setup -> masking is a no-op, ignored
    const float* Wc   = (const float*)d_in[2];
    const float* Wsim = (const float*)d_in[3];
    const float* Wrel = (const float*)d_in[4];
    const float* bmat = (const float*)d_in[5];
    float* out = (float*)d_out;

    char* ws = (char*)d_ws;
    size_t off = 0;
    float* qbuf = (float*)(ws + off); off += (size_t)BB * SS * SS * 4;  // 20.48 MB
    float* drep = (float*)(ws + off); off += (size_t)BB * HH * 4;       // 1.57 MB
    float* tmat = (float*)(ws + off); off += (size_t)BB * HH * 4;       // 1.57 MB
    float* avec = (float*)(ws + off); off += (size_t)BB * SS * 4;       // 0.2 MB
    // Y chunk: largest batch-chunk that fits in remaining ws (chunkB*100 divisible by 128)
    int chunkB = 512;
    while (chunkB > 32 && off + (size_t)chunkB * SS * HH * 4 > ws_size) chunkB >>= 1;
    float* Ybuf = (float*)(ws + off);

    k_drep<<<BB, 256, 0, stream>>>(X, drep);
    k_gemm_nt<<<dim3(HH / 64, BB / 64), 256, 0, stream>>>(drep, Wrel, tmat, HH, HH);
    k_contrel<<<BB, 256, 0, stream>>>(X, Wc, tmat, bmat, avec);
    for (int c = 0; c < BB; c += chunkB) {
        k_gemm1<<<dim3(HH / 64, chunkB * SS / 128), 256, 0, stream>>>(X + (size_t)c * SS * HH, Wsim, Ybuf);
        k_gemm2<<<chunkB, 256, 0, stream>>>(Ybuf, X, avec, qbuf, c);
    }
    k_solve<<<BB, 128, 0, stream>>>(qbuf, out);
}

// Round 2
// 974.883 us; speedup vs baseline: 1.4902x; 1.4902x over previous
//
#include <hip/hip_runtime.h>
#include <math.h>

#define BB 512
#define SS 100
#define HH 768
#define CB 128   // batch chunk: 4*CB*SS*HH*2B = 78.6MB Y+X split buffers

typedef __bf16 bf16x8 __attribute__((ext_vector_type(8)));
typedef __bf16 bf16x4 __attribute__((ext_vector_type(4)));
typedef float f32x4 __attribute__((ext_vector_type(4)));

__device__ __forceinline__ void gld16(const void* g, void* l) {
    __builtin_amdgcn_global_load_lds((const __attribute__((address_space(1))) char*)g,
                                     (__attribute__((address_space(3))) char*)l, 16, 0, 0);
}

// ---------------- K0: d_rep[b,h] = mean_s X[b,s,h] ----------------
__global__ __launch_bounds__(256) void k_drep(const float* __restrict__ X,
                                              float* __restrict__ drep) {
    int b = blockIdx.x;
    const float* xb = X + (size_t)b * SS * HH;
    for (int h = threadIdx.x; h < HH; h += 256) {
        float s = 0.f;
        #pragma unroll 4
        for (int i = 0; i < SS; ++i) s += xb[(size_t)i * HH + h];
        drep[(size_t)b * HH + h] = s * (1.0f / SS);
    }
}

// ---------------- K1: t = d_rep @ W_rel^T  (fp32 NT, 64x64x16; 0.6 GFLOP) ----------------
__global__ __launch_bounds__(256) void k_gemm_nt(const float* __restrict__ A,
                                                 const float* __restrict__ Bm,
                                                 float* __restrict__ C,
                                                 int N, int K) {
    __shared__ float As[64 * 20];
    __shared__ float Bs[64 * 20];
    int tid = threadIdx.x;
    int ty = tid >> 4, tx = tid & 15;
    int m0 = blockIdx.y * 64, n0 = blockIdx.x * 64;
    int lr = tid >> 2, lc = (tid & 3) * 4;
    float acc[4][4] = {};
    for (int kt = 0; kt < K; kt += 16) {
        *(float4*)(As + lr * 20 + lc) = *(const float4*)(A + (size_t)(m0 + lr) * K + kt + lc);
        *(float4*)(Bs + lr * 20 + lc) = *(const float4*)(Bm + (size_t)(n0 + lr) * K + kt + lc);
        __syncthreads();
        #pragma unroll
        for (int k = 0; k < 16; k += 2) {
            float2 ar[4], br[4];
            #pragma unroll
            for (int ii = 0; ii < 4; ++ii) ar[ii] = *(const float2*)(As + (ty + 16 * ii) * 20 + k);
            #pragma unroll
            for (int jj = 0; jj < 4; ++jj) br[jj] = *(const float2*)(Bs + (tx + 16 * jj) * 20 + k);
            #pragma unroll
            for (int ii = 0; ii < 4; ++ii)
                #pragma unroll
                for (int jj = 0; jj < 4; ++jj)
                    acc[ii][jj] = fmaf(ar[ii].y, br[jj].y, fmaf(ar[ii].x, br[jj].x, acc[ii][jj]));
        }
        __syncthreads();
    }
    #pragma unroll
    for (int ii = 0; ii < 4; ++ii)
        #pragma unroll
        for (int jj = 0; jj < 4; ++jj)
            C[(size_t)(m0 + ty + 16 * ii) * N + n0 + tx + 16 * jj] = acc[ii][jj];
}

// ---------------- K2: a[b,i] = X[b,i]·(Wc + t[b]) + b00 ----------------
__global__ __launch_bounds__(256) void k_contrel(const float* __restrict__ X,
                                                 const float* __restrict__ Wc,
                                                 const float* __restrict__ tmat,
                                                 const float* __restrict__ bmat,
                                                 float* __restrict__ avec) {
    __shared__ float u[HH];
    int b = blockIdx.x;
    for (int h = threadIdx.x; h < HH; h += 256)
        u[h] = Wc[h] + tmat[(size_t)b * HH + h];
    __syncthreads();
    int wave = threadIdx.x >> 6, lane = threadIdx.x & 63;
    float b00 = bmat[0];
    for (int r = wave; r < SS; r += 4) {
        const float* xr = X + ((size_t)b * SS + r) * HH;
        float s = 0.f;
        for (int h = lane; h < HH; h += 64) s = fmaf(xr[h], u[h], s);
        #pragma unroll
        for (int off = 32; off > 0; off >>= 1) s += __shfl_down(s, off);
        if (lane == 0) avec[(size_t)b * SS + r] = s + b00;
    }
}

// ---------------- K_split: fp32 -> (hi, lo) bf16, elementwise x4 ----------------
__global__ __launch_bounds__(256) void k_split(const float* __restrict__ src,
                                               __bf16* __restrict__ h,
                                               __bf16* __restrict__ l, int n4) {
    int i = blockIdx.x * 256 + threadIdx.x;
    if (i >= n4) return;
    float4 v = ((const float4*)src)[i];
    bf16x4 hv, lv;
    hv[0] = (__bf16)v.x; lv[0] = (__bf16)(v.x - (float)hv[0]);
    hv[1] = (__bf16)v.y; lv[1] = (__bf16)(v.y - (float)hv[1]);
    hv[2] = (__bf16)v.z; lv[2] = (__bf16)(v.z - (float)hv[2]);
    hv[3] = (__bf16)v.w; lv[3] = (__bf16)(v.w - (float)hv[3]);
    ((bf16x4*)h)[i] = hv;
    ((bf16x4*)l)[i] = lv;
}

// ---------------- K_splitw: W(K x N) -> Wt_h/Wt_l (N x K) bf16 split ----------------
__global__ __launch_bounds__(256) void k_splitw(const float* __restrict__ W,
                                                __bf16* __restrict__ th,
                                                __bf16* __restrict__ tl) {
    __shared__ float tile[32][33];
    int bn = blockIdx.x * 32, bk = blockIdx.y * 32;
    int tx = threadIdx.x & 31, ty = threadIdx.x >> 5;
    for (int r = ty; r < 32; r += 8)
        tile[r][tx] = W[(size_t)(bk + r) * HH + bn + tx];   // tile[k_loc][n_loc]
    __syncthreads();
    for (int r = ty; r < 32; r += 8) {
        float v = tile[tx][r];                              // W[bk+tx][bn+r]
        __bf16 hv = (__bf16)v;
        size_t idx = (size_t)(bn + r) * HH + bk + tx;       // out[n][k]
        th[idx] = hv;
        tl[idx] = (__bf16)(v - (float)hv);
    }
}

// ---------------- K3: GEMM1 MFMA  Y = X @ W  (NT on split-bf16, 128x128, BK=32) ----------------
// A = Xh/Xl [M x 768] row-major; B = Wt [768(n) x 768(k)] row-major (pre-transposed).
// Y stored as bf16 hi/lo split for GEMM2.
__global__ __launch_bounds__(256) void k_gemm1_mfma(const __bf16* __restrict__ Ah_g,
                                                    const __bf16* __restrict__ Al_g,
                                                    const __bf16* __restrict__ Bh_g,
                                                    const __bf16* __restrict__ Bl_g,
                                                    __bf16* __restrict__ Yh,
                                                    __bf16* __restrict__ Yl) {
    __shared__ __align__(16) __bf16 lds[4 * 4096];
    __bf16* As_h = lds;
    __bf16* As_l = lds + 4096;
    __bf16* Bs_h = lds + 8192;
    __bf16* Bs_l = lds + 12288;
    const int tid = threadIdx.x;
    const int wave = tid >> 6, lane = tid & 63;
    const int wy = wave >> 1, wx = wave & 1;
    const size_t m0 = (size_t)blockIdx.y * 128;
    const int n0 = blockIdx.x * 128;

    // staging: wave w fills LDS bytes [w*2048 + t*1024, +1024) of each tile
    const int srow = wave * 32 + (lane >> 2);   // + t*16
    const int scol = (lane & 3) * 8;            // k elems within BK=32
    const int lds_base = wave * 1024;           // __bf16 elems: wave*2048 bytes

    const int arow = wy * 64 + (lane & 15);
    const int brow = wx * 64 + (lane & 15);
    const int koff = (lane >> 4) * 8;           // elems

    f32x4 acc[4][4] = {};
    for (int kt = 0; kt < HH; kt += 32) {
        const size_t ga0 = (m0 + srow) * HH + kt + scol;
        const size_t ga1 = ga0 + (size_t)16 * HH;
        const size_t gb0 = (size_t)(n0 + srow) * HH + kt + scol;
        const size_t gb1 = gb0 + (size_t)16 * HH;
        gld16(Ah_g + ga0, As_h + lds_base);
        gld16(Ah_g + ga1, As_h + lds_base + 512);
        gld16(Al_g + ga0, As_l + lds_base);
        gld16(Al_g + ga1, As_l + lds_base + 512);
        gld16(Bh_g + gb0, Bs_h + lds_base);
        gld16(Bh_g + gb1, Bs_h + lds_base + 512);
        gld16(Bl_g + gb0, Bs_l + lds_base);
        gld16(Bl_g + gb1, Bs_l + lds_base + 512);
        __syncthreads();
        bf16x8 fah[4], fal[4], fbh[4], fbl[4];
        #pragma unroll
        for (int t = 0; t < 4; ++t) {
            fah[t] = *(const bf16x8*)(As_h + (arow + t * 16) * 32 + koff);
            fal[t] = *(const bf16x8*)(As_l + (arow + t * 16) * 32 + koff);
            fbh[t] = *(const bf16x8*)(Bs_h + (brow + t * 16) * 32 + koff);
            fbl[t] = *(const bf16x8*)(Bs_l + (brow + t * 16) * 32 + koff);
        }
        #pragma unroll
        for (int ti = 0; ti < 4; ++ti)
            #pragma unroll
            for (int tj = 0; tj < 4; ++tj) {
                acc[ti][tj] = __builtin_amdgcn_mfma_f32_16x16x32_bf16(fal[ti], fbh[tj], acc[ti][tj], 0, 0, 0);
                acc[ti][tj] = __builtin_amdgcn_mfma_f32_16x16x32_bf16(fah[ti], fbl[tj], acc[ti][tj], 0, 0, 0);
                acc[ti][tj] = __builtin_amdgcn_mfma_f32_16x16x32_bf16(fah[ti], fbh[tj], acc[ti][tj], 0, 0, 0);
            }
        __syncthreads();
    }
    // C/D: col = lane&15, row = (lane>>4)*4 + r  [m89-verified]
    #pragma unroll
    for (int ti = 0; ti < 4; ++ti) {
        int row0 = wy * 64 + ti * 16 + (lane >> 4) * 4;
        #pragma unroll
        for (int tj = 0; tj < 4; ++tj) {
            int col = n0 + wx * 64 + tj * 16 + (lane & 15);
            #pragma unroll
            for (int r = 0; r < 4; ++r) {
                float v = acc[ti][tj][r];
                __bf16 hv = (__bf16)v;
                size_t idx = (m0 + row0 + r) * HH + col;
                Yh[idx] = hv;
                Yl[idx] = (__bf16)(v - (float)hv);
            }
        }
    }
}

// ---------------- K4: GEMM2 MFMA  q[b] = sigmoid(Y[b] @ X[b]^T + a[b,i]) ----------------
// One block per batch; 128x128 tile covers 100x100 (staging rows clamped to 99).
__global__ __launch_bounds__(256) void k_gemm2_mfma(const __bf16* __restrict__ Yh,
                                                    const __bf16* __restrict__ Yl,
                                                    const __bf16* __restrict__ Xh,
                                                    const __bf16* __restrict__ Xl,
                                                    const float* __restrict__ avec,
                                                    float* __restrict__ q, int b_off) {
    __shared__ __align__(16) __bf16 lds[4 * 4096];
    __bf16* As_h = lds;
    __bf16* As_l = lds + 4096;
    __bf16* Bs_h = lds + 8192;
    __bf16* Bs_l = lds + 12288;
    const int bl = blockIdx.x;
    const int b = b_off + bl;
    const __bf16* Ah_g = Yh + (size_t)bl * SS * HH;
    const __bf16* Al_g = Yl + (size_t)bl * SS * HH;
    const __bf16* Bh_g = Xh + (size_t)bl * SS * HH;
    const __bf16* Bl_g = Xl + (size_t)bl * SS * HH;
    const int tid = threadIdx.x;
    const int wave = tid >> 6, lane = tid & 63;
    const int wy = wave >> 1, wx = wave & 1;

    const int srow_raw = wave * 32 + (lane >> 2);
    const int scol = (lane & 3) * 8;
    const int lds_base = wave * 1024;
    const int r0 = srow_raw < SS ? srow_raw : SS - 1;            // t=0 rows
    const int r1 = (srow_raw + 16) < SS ? (srow_raw + 16) : SS - 1; // t=1 rows

    const int arow = wy * 64 + (lane & 15);
    const int brow = wx * 64 + (lane & 15);
    const int koff = (lane >> 4) * 8;

    f32x4 acc[4][4] = {};
    for (int kt = 0; kt < HH; kt += 32) {
        const size_t ga0 = (size_t)r0 * HH + kt + scol;
        const size_t ga1 = (size_t)r1 * HH + kt + scol;
        gld16(Ah_g + ga0, As_h + lds_base);
        gld16(Ah_g + ga1, As_h + lds_base + 512);
        gld16(Al_g + ga0, As_l + lds_base);
        gld16(Al_g + ga1, As_l + lds_base + 512);
        gld16(Bh_g + ga0, Bs_h + lds_base);
        gld16(Bh_g + ga1, Bs_h + lds_base + 512);
        gld16(Bl_g + ga0, Bs_l + lds_base);
        gld16(Bl_g + ga1, Bs_l + lds_base + 512);
        __syncthreads();
        bf16x8 fah[4], fal[4], fbh[4], fbl[4];
        #pragma unroll
        for (int t = 0; t < 4; ++t) {
            fah[t] = *(const bf16x8*)(As_h + (arow + t * 16) * 32 + koff);
            fal[t] = *(const bf16x8*)(As_l + (arow + t * 16) * 32 + koff);
            fbh[t] = *(const bf16x8*)(Bs_h + (brow + t * 16) * 32 + koff);
            fbl[t] = *(const bf16x8*)(Bs_l + (brow + t * 16) * 32 + koff);
        }
        #pragma unroll
        for (int ti = 0; ti < 4; ++ti)
            #pragma unroll
            for (int tj = 0; tj < 4; ++tj) {
                acc[ti][tj] = __builtin_amdgcn_mfma_f32_16x16x32_bf16(fal[ti], fbh[tj], acc[ti][tj], 0, 0, 0);
                acc[ti][tj] = __builtin_amdgcn_mfma_f32_16x16x32_bf16(fah[ti], fbl[tj], acc[ti][tj], 0, 0, 0);
                acc[ti][tj] = __builtin_amdgcn_mfma_f32_16x16x32_bf16(fah[ti], fbh[tj], acc[ti][tj], 0, 0, 0);
            }
        __syncthreads();
    }
    float* qb = q + (size_t)b * SS * SS;
    const float* av = avec + (size_t)b * SS;
    #pragma unroll
    for (int ti = 0; ti < 4; ++ti) {
        int i0 = wy * 64 + ti * 16 + (lane >> 4) * 4;
        if (i0 >= SS) continue;
        #pragma unroll
        for (int tj = 0; tj < 4; ++tj) {
            int j = wx * 64 + tj * 16 + (lane & 15);
            if (j >= SS) continue;
            #pragma unroll
            for (int r = 0; r < 4; ++r) {
                int i = i0 + r;
                if (i >= SS) continue;
                float v = acc[ti][tj][r] + av[i];
                qb[(size_t)i * SS + j] = 1.0f / (1.0f + __expf(-v));
            }
        }
    }
}

// ---------------- K5: colsum + fixed-point solve (0.8-contraction, 64 iters) ----------------
__global__ __launch_bounds__(128) void k_solve(const float* __restrict__ q,
                                               float* __restrict__ out) {
    __shared__ float m[SS * 101];
    __shared__ float cs[SS];
    __shared__ float x0[SS], x1[SS];
    int b = blockIdx.x, tid = threadIdx.x;
    const float* qb = q + (size_t)b * SS * SS;
    for (int e4 = tid; e4 < SS * SS / 4; e4 += 128) {
        float4 v = *(const float4*)(qb + (size_t)e4 * 4);
        int e = e4 * 4, r = e / 100, c = e - r * 100;
        m[r * 101 + c]     = v.x;
        m[r * 101 + c + 1] = v.y;
        m[r * 101 + c + 2] = v.z;
        m[r * 101 + c + 3] = v.w;
    }
    __syncthreads();
    if (tid < SS) {
        float s = 0.f;
        for (int i = 0; i < SS; ++i) s += m[i * 101 + tid];
        cs[tid] = 0.8f / s;
    }
    __syncthreads();
    if (tid < SS) {
        float f = cs[tid];
        for (int i = 0; i < SS; ++i) m[i * 101 + tid] *= f;
        x0[tid] = 1.0f / SS;
    }
    __syncthreads();
    float* xa = x0; float* xb = x1;
    for (int it = 0; it < 64; ++it) {
        if (tid < SS) {
            float s = 0.002f;
            #pragma unroll 4
            for (int j = 0; j < SS; ++j) s = fmaf(m[tid * 101 + j], xa[j], s);
            xb[tid] = s;
        }
        __syncthreads();
        float* tmp = xa; xa = xb; xb = tmp;
    }
    if (tid < SS) out[(size_t)b * SS + tid] = xa[tid];
}

extern "C" void kernel_launch(void* const* d_in, const int* in_sizes, int n_in,
                              void* d_out, int out_size, void* d_ws, size_t ws_size,
                              hipStream_t stream) {
    (void)in_sizes; (void)n_in; (void)out_size; (void)ws_size;
    const float* X    = (const float*)d_in[0];
    const float* Wc   = (const float*)d_in[2];
    const float* Wsim = (const float*)d_in[3];
    const float* Wrel = (const float*)d_in[4];
    const float* bmat = (const float*)d_in[5];
    float* out = (float*)d_out;

    char* ws = (char*)d_ws;
    size_t off = 0;
    float*  qbuf = (float*)(ws + off);  off += (size_t)BB * SS * SS * 4;   // 20.48 MB
    float*  drep = (float*)(ws + off);  off += (size_t)BB * HH * 4;        // 1.57 MB
    float*  tmat = (float*)(ws + off);  off += (size_t)BB * HH * 4;        // 1.57 MB
    float*  avec = (float*)(ws + off);  off += (size_t)BB * SS * 4;        // 0.20 MB
    __bf16* Wth  = (__bf16*)(ws + off); off += (size_t)HH * HH * 2;        // 1.18 MB
    __bf16* Wtl  = (__bf16*)(ws + off); off += (size_t)HH * HH * 2;        // 1.18 MB
    __bf16* Xh   = (__bf16*)(ws + off); off += (size_t)CB * SS * HH * 2;   // 19.66 MB
    __bf16* Xl   = (__bf16*)(ws + off); off += (size_t)CB * SS * HH * 2;
    __bf16* Yh   = (__bf16*)(ws + off); off += (size_t)CB * SS * HH * 2;
    __bf16* Yl   = (__bf16*)(ws + off); off += (size_t)CB * SS * HH * 2;   // total ~105 MB

    k_drep<<<BB, 256, 0, stream>>>(X, drep);
    k_gemm_nt<<<dim3(HH / 64, BB / 64), 256, 0, stream>>>(drep, Wrel, tmat, HH, HH);
    k_contrel<<<BB, 256, 0, stream>>>(X, Wc, tmat, bmat, avec);
    k_splitw<<<dim3(HH / 32, HH / 32), 256, 0, stream>>>(Wsim, Wth, Wtl);

    const int n4 = CB * SS * HH / 4;
    for (int c = 0; c < BB; c += CB) {
        k_split<<<(n4 + 255) / 256, 256, 0, stream>>>(X + (size_t)c * SS * HH, Xh, Xl, n4);
        k_gemm1_mfma<<<dim3(HH / 128, CB * SS / 128), 256, 0, stream>>>(Xh, Xl, Wth, Wtl, Yh, Yl);
        k_gemm2_mfma<<<CB, 256, 0, stream>>>(Yh, Yl, Xh, Xl, avec, qbuf, c);
    }
    k_solve<<<BB, 128, 0, stream>>>(qbuf, out);
}

// Round 3
// 937.146 us; speedup vs baseline: 1.5502x; 1.0403x over previous
//
#include <hip/hip_runtime.h>
#include <math.h>

#define BB 512
#define SS 100
#define HH 768
#define CB 128   // batch chunk: 4*CB*SS*HH*2B = 78.6MB Y+X split buffers

typedef __bf16 bf16x8 __attribute__((ext_vector_type(8)));
typedef __bf16 bf16x4 __attribute__((ext_vector_type(4)));
typedef float f32x4 __attribute__((ext_vector_type(4)));

__device__ __forceinline__ void gld16(const void* g, void* l) {
    __builtin_amdgcn_global_load_lds((const __attribute__((address_space(1))) char*)g,
                                     (__attribute__((address_space(3))) char*)l, 16, 0, 0);
}

// ---------------- K0: d_rep[b,h] = mean_s X[b,s,h] ----------------
__global__ __launch_bounds__(256) void k_drep(const float* __restrict__ X,
                                              float* __restrict__ drep) {
    int b = blockIdx.x;
    const float* xb = X + (size_t)b * SS * HH;
    for (int h = threadIdx.x; h < HH; h += 256) {
        float s = 0.f;
        #pragma unroll 4
        for (int i = 0; i < SS; ++i) s += xb[(size_t)i * HH + h];
        drep[(size_t)b * HH + h] = s * (1.0f / SS);
    }
}

// ---------------- K1: t = d_rep @ W_rel^T  (fp32 NT, 64x64x16; 0.6 GFLOP) ----------------
__global__ __launch_bounds__(256) void k_gemm_nt(const float* __restrict__ A,
                                                 const float* __restrict__ Bm,
                                                 float* __restrict__ C,
                                                 int N, int K) {
    __shared__ float As[64 * 20];
    __shared__ float Bs[64 * 20];
    int tid = threadIdx.x;
    int ty = tid >> 4, tx = tid & 15;
    int m0 = blockIdx.y * 64, n0 = blockIdx.x * 64;
    int lr = tid >> 2, lc = (tid & 3) * 4;
    float acc[4][4] = {};
    for (int kt = 0; kt < K; kt += 16) {
        *(float4*)(As + lr * 20 + lc) = *(const float4*)(A + (size_t)(m0 + lr) * K + kt + lc);
        *(float4*)(Bs + lr * 20 + lc) = *(const float4*)(Bm + (size_t)(n0 + lr) * K + kt + lc);
        __syncthreads();
        #pragma unroll
        for (int k = 0; k < 16; k += 2) {
            float2 ar[4], br[4];
            #pragma unroll
            for (int ii = 0; ii < 4; ++ii) ar[ii] = *(const float2*)(As + (ty + 16 * ii) * 20 + k);
            #pragma unroll
            for (int jj = 0; jj < 4; ++jj) br[jj] = *(const float2*)(Bs + (tx + 16 * jj) * 20 + k);
            #pragma unroll
            for (int ii = 0; ii < 4; ++ii)
                #pragma unroll
                for (int jj = 0; jj < 4; ++jj)
                    acc[ii][jj] = fmaf(ar[ii].y, br[jj].y, fmaf(ar[ii].x, br[jj].x, acc[ii][jj]));
        }
        __syncthreads();
    }
    #pragma unroll
    for (int ii = 0; ii < 4; ++ii)
        #pragma unroll
        for (int jj = 0; jj < 4; ++jj)
            C[(size_t)(m0 + ty + 16 * ii) * N + n0 + tx + 16 * jj] = acc[ii][jj];
}

// ---------------- K2: a[b,i] = X[b,i]·(Wc + t[b]) + b00 ----------------
__global__ __launch_bounds__(256) void k_contrel(const float* __restrict__ X,
                                                 const float* __restrict__ Wc,
                                                 const float* __restrict__ tmat,
                                                 const float* __restrict__ bmat,
                                                 float* __restrict__ avec) {
    __shared__ float u[HH];
    int b = blockIdx.x;
    for (int h = threadIdx.x; h < HH; h += 256)
        u[h] = Wc[h] + tmat[(size_t)b * HH + h];
    __syncthreads();
    int wave = threadIdx.x >> 6, lane = threadIdx.x & 63;
    float b00 = bmat[0];
    for (int r = wave; r < SS; r += 4) {
        const float* xr = X + ((size_t)b * SS + r) * HH;
        float s = 0.f;
        for (int h = lane; h < HH; h += 64) s = fmaf(xr[h], u[h], s);
        #pragma unroll
        for (int off = 32; off > 0; off >>= 1) s += __shfl_down(s, off);
        if (lane == 0) avec[(size_t)b * SS + r] = s + b00;
    }
}

// ---------------- K_split: fp32 -> (hi, lo) bf16, elementwise x4 ----------------
__global__ __launch_bounds__(256) void k_split(const float* __restrict__ src,
                                               __bf16* __restrict__ h,
                                               __bf16* __restrict__ l, int n4) {
    int i = blockIdx.x * 256 + threadIdx.x;
    if (i >= n4) return;
    float4 v = ((const float4*)src)[i];
    bf16x4 hv, lv;
    hv[0] = (__bf16)v.x; lv[0] = (__bf16)(v.x - (float)hv[0]);
    hv[1] = (__bf16)v.y; lv[1] = (__bf16)(v.y - (float)hv[1]);
    hv[2] = (__bf16)v.z; lv[2] = (__bf16)(v.z - (float)hv[2]);
    hv[3] = (__bf16)v.w; lv[3] = (__bf16)(v.w - (float)hv[3]);
    ((bf16x4*)h)[i] = hv;
    ((bf16x4*)l)[i] = lv;
}

// ---------------- K_splitw: W(K x N) -> Wt_h/Wt_l (N x K) bf16 split ----------------
__global__ __launch_bounds__(256) void k_splitw(const float* __restrict__ W,
                                                __bf16* __restrict__ th,
                                                __bf16* __restrict__ tl) {
    __shared__ float tile[32][33];
    int bn = blockIdx.x * 32, bk = blockIdx.y * 32;
    int tx = threadIdx.x & 31, ty = threadIdx.x >> 5;
    for (int r = ty; r < 32; r += 8)
        tile[r][tx] = W[(size_t)(bk + r) * HH + bn + tx];   // tile[k_loc][n_loc]
    __syncthreads();
    for (int r = ty; r < 32; r += 8) {
        float v = tile[tx][r];                              // W[bk+tx][bn+r]
        __bf16 hv = (__bf16)v;
        size_t idx = (size_t)(bn + r) * HH + bk + tx;       // out[n][k]
        th[idx] = hv;
        tl[idx] = (__bf16)(v - (float)hv);
    }
}

// ---------------- K3: GEMM1 MFMA  Y = X @ W  (NT on split-bf16, 128x128, BK=32) ----------------
__global__ __launch_bounds__(256) void k_gemm1_mfma(const __bf16* __restrict__ Ah_g,
                                                    const __bf16* __restrict__ Al_g,
                                                    const __bf16* __restrict__ Bh_g,
                                                    const __bf16* __restrict__ Bl_g,
                                                    __bf16* __restrict__ Yh,
                                                    __bf16* __restrict__ Yl) {
    __shared__ __align__(16) __bf16 lds[4 * 4096];
    __bf16* As_h = lds;
    __bf16* As_l = lds + 4096;
    __bf16* Bs_h = lds + 8192;
    __bf16* Bs_l = lds + 12288;
    const int tid = threadIdx.x;
    const int wave = tid >> 6, lane = tid & 63;
    const int wy = wave >> 1, wx = wave & 1;
    const size_t m0 = (size_t)blockIdx.y * 128;
    const int n0 = blockIdx.x * 128;

    const int srow = wave * 32 + (lane >> 2);
    const int scol = (lane & 3) * 8;
    const int lds_base = wave * 1024;

    const int arow = wy * 64 + (lane & 15);
    const int brow = wx * 64 + (lane & 15);
    const int koff = (lane >> 4) * 8;

    f32x4 acc[4][4] = {};
    for (int kt = 0; kt < HH; kt += 32) {
        const size_t ga0 = (m0 + srow) * HH + kt + scol;
        const size_t ga1 = ga0 + (size_t)16 * HH;
        const size_t gb0 = (size_t)(n0 + srow) * HH + kt + scol;
        const size_t gb1 = gb0 + (size_t)16 * HH;
        gld16(Ah_g + ga0, As_h + lds_base);
        gld16(Ah_g + ga1, As_h + lds_base + 512);
        gld16(Al_g + ga0, As_l + lds_base);
        gld16(Al_g + ga1, As_l + lds_base + 512);
        gld16(Bh_g + gb0, Bs_h + lds_base);
        gld16(Bh_g + gb1, Bs_h + lds_base + 512);
        gld16(Bl_g + gb0, Bs_l + lds_base);
        gld16(Bl_g + gb1, Bs_l + lds_base + 512);
        __syncthreads();
        bf16x8 fah[4], fal[4], fbh[4], fbl[4];
        #pragma unroll
        for (int t = 0; t < 4; ++t) {
            fah[t] = *(const bf16x8*)(As_h + (arow + t * 16) * 32 + koff);
            fal[t] = *(const bf16x8*)(As_l + (arow + t * 16) * 32 + koff);
            fbh[t] = *(const bf16x8*)(Bs_h + (brow + t * 16) * 32 + koff);
            fbl[t] = *(const bf16x8*)(Bs_l + (brow + t * 16) * 32 + koff);
        }
        #pragma unroll
        for (int ti = 0; ti < 4; ++ti)
            #pragma unroll
            for (int tj = 0; tj < 4; ++tj) {
                acc[ti][tj] = __builtin_amdgcn_mfma_f32_16x16x32_bf16(fal[ti], fbh[tj], acc[ti][tj], 0, 0, 0);
                acc[ti][tj] = __builtin_amdgcn_mfma_f32_16x16x32_bf16(fah[ti], fbl[tj], acc[ti][tj], 0, 0, 0);
                acc[ti][tj] = __builtin_amdgcn_mfma_f32_16x16x32_bf16(fah[ti], fbh[tj], acc[ti][tj], 0, 0, 0);
            }
        __syncthreads();
    }
    #pragma unroll
    for (int ti = 0; ti < 4; ++ti) {
        int row0 = wy * 64 + ti * 16 + (lane >> 4) * 4;
        #pragma unroll
        for (int tj = 0; tj < 4; ++tj) {
            int col = n0 + wx * 64 + tj * 16 + (lane & 15);
            #pragma unroll
            for (int r = 0; r < 4; ++r) {
                float v = acc[ti][tj][r];
                __bf16 hv = (__bf16)v;
                size_t idx = (m0 + row0 + r) * HH + col;
                Yh[idx] = hv;
                Yl[idx] = (__bf16)(v - (float)hv);
            }
        }
    }
}

// ---------------- K4: GEMM2 MFMA  q[b] = sigmoid(Y[b] @ X[b]^T + a[b,i]) ----------------
// 64x128 output tile, 2 blocks per batch -> 2*CB blocks/dispatch (full-GPU grid).
__global__ __launch_bounds__(256) void k_gemm2_mfma(const __bf16* __restrict__ Yh,
                                                    const __bf16* __restrict__ Yl,
                                                    const __bf16* __restrict__ Xh,
                                                    const __bf16* __restrict__ Xl,
                                                    const float* __restrict__ avec,
                                                    float* __restrict__ q, int b_off) {
    __shared__ __align__(16) __bf16 lds[12288];   // A 2x2048 + B 2x4096 = 24KB
    __bf16* As_h = lds;
    __bf16* As_l = lds + 2048;
    __bf16* Bs_h = lds + 4096;
    __bf16* Bs_l = lds + 8192;
    const int bl = blockIdx.x >> 1;
    const int rh = (blockIdx.x & 1) * 64;          // row-half offset
    const int b = b_off + bl;
    const __bf16* Ah_g = Yh + (size_t)bl * SS * HH;
    const __bf16* Al_g = Yl + (size_t)bl * SS * HH;
    const __bf16* Bh_g = Xh + (size_t)bl * SS * HH;
    const __bf16* Bl_g = Xl + (size_t)bl * SS * HH;
    const int tid = threadIdx.x;
    const int wave = tid >> 6, lane = tid & 63;
    const int wy = wave >> 1, wx = wave & 1;

    // A staging: 64 rows x 32k, 1 pass; thread t -> row rh + (t>>2), col (t&3)*8
    int ar_ = rh + (tid >> 2); if (ar_ >= SS) ar_ = SS - 1;
    const int scol = (lane & 3) * 8;
    const int a_base = wave * 512;                 // elems
    // B staging: 128 rows x 32k, 2 passes; rows wave*32 + (lane>>2) + {0,16}
    const int sbrow = wave * 32 + (lane >> 2);
    const int b_base = wave * 1024;
    const int br0 = sbrow < SS ? sbrow : SS - 1;
    const int br1 = (sbrow + 16) < SS ? (sbrow + 16) : SS - 1;

    const int arow = wy * 32 + (lane & 15);
    const int brow = wx * 64 + (lane & 15);
    const int koff = (lane >> 4) * 8;

    f32x4 acc[2][4] = {};
    for (int kt = 0; kt < HH; kt += 32) {
        const size_t ga  = (size_t)ar_ * HH + kt + scol;
        const size_t gb0 = (size_t)br0 * HH + kt + scol;
        const size_t gb1 = (size_t)br1 * HH + kt + scol;
        gld16(Ah_g + ga,  As_h + a_base);
        gld16(Al_g + ga,  As_l + a_base);
        gld16(Bh_g + gb0, Bs_h + b_base);
        gld16(Bh_g + gb1, Bs_h + b_base + 512);
        gld16(Bl_g + gb0, Bs_l + b_base);
        gld16(Bl_g + gb1, Bs_l + b_base + 512);
        __syncthreads();
        bf16x8 fah[2], fal[2], fbh[4], fbl[4];
        #pragma unroll
        for (int t = 0; t < 2; ++t) {
            fah[t] = *(const bf16x8*)(As_h + (arow + t * 16) * 32 + koff);
            fal[t] = *(const bf16x8*)(As_l + (arow + t * 16) * 32 + koff);
        }
        #pragma unroll
        for (int t = 0; t < 4; ++t) {
            fbh[t] = *(const bf16x8*)(Bs_h + (brow + t * 16) * 32 + koff);
            fbl[t] = *(const bf16x8*)(Bs_l + (brow + t * 16) * 32 + koff);
        }
        #pragma unroll
        for (int ti = 0; ti < 2; ++ti)
            #pragma unroll
            for (int tj = 0; tj < 4; ++tj) {
                acc[ti][tj] = __builtin_amdgcn_mfma_f32_16x16x32_bf16(fal[ti], fbh[tj], acc[ti][tj], 0, 0, 0);
                acc[ti][tj] = __builtin_amdgcn_mfma_f32_16x16x32_bf16(fah[ti], fbl[tj], acc[ti][tj], 0, 0, 0);
                acc[ti][tj] = __builtin_amdgcn_mfma_f32_16x16x32_bf16(fah[ti], fbh[tj], acc[ti][tj], 0, 0, 0);
            }
        __syncthreads();
    }
    float* qb = q + (size_t)b * SS * SS;
    const float* av = avec + (size_t)b * SS;
    #pragma unroll
    for (int ti = 0; ti < 2; ++ti) {
        int i0 = rh + wy * 32 + ti * 16 + (lane >> 4) * 4;
        if (i0 >= SS) continue;
        #pragma unroll
        for (int tj = 0; tj < 4; ++tj) {
            int j = wx * 64 + tj * 16 + (lane & 15);
            if (j >= SS) continue;
            #pragma unroll
            for (int r = 0; r < 4; ++r) {
                int i = i0 + r;
                if (i >= SS) continue;
                float v = acc[ti][tj][r] + av[i];
                qb[(size_t)i * SS + j] = 1.0f / (1.0f + __expf(-v));
            }
        }
    }
}

// ---------------- K5: colsum + fixed-point solve, M held in registers ----------------
// x = 0.002 + (0.8 qD) x contracts at 0.8/iter; 56 iters -> err <= 2*0.8^56 = 7.2e-6.
__global__ __launch_bounds__(128) void k_solve(const float* __restrict__ q,
                                               float* __restrict__ out) {
    __shared__ __align__(16) float m[SS * SS];    // 40 KB, row-major (same as q)
    __shared__ __align__(16) float csinv[SS];
    __shared__ __align__(16) float x0[SS], x1[SS];
    int b = blockIdx.x, tid = threadIdx.x;
    const float* qb = q + (size_t)b * SS * SS;
    for (int e4 = tid; e4 < SS * SS / 4; e4 += 128)
        *(float4*)(m + e4 * 4) = *(const float4*)(qb + (size_t)e4 * 4);
    __syncthreads();
    if (tid < SS) {
        float s = 0.f;
        for (int i = 0; i < SS; ++i) s += m[i * SS + tid];   // lanes consecutive: conflict-free
        csinv[tid] = 0.8f / s;
        x0[tid] = 1.0f / SS;
    }
    __syncthreads();
    // thread t owns row t of M' = 0.8 * q * D^-1, in registers (25 x float4 = 100 VGPR)
    float4 mreg[25];
    if (tid < SS) {
        #pragma unroll
        for (int j4 = 0; j4 < 25; ++j4) {
            float4 mv = *(const float4*)(m + tid * SS + j4 * 4);
            float4 cv = *(const float4*)(csinv + j4 * 4);
            mreg[j4].x = mv.x * cv.x;
            mreg[j4].y = mv.y * cv.y;
            mreg[j4].z = mv.z * cv.z;
            mreg[j4].w = mv.w * cv.w;
        }
    } else {
        #pragma unroll
        for (int j4 = 0; j4 < 25; ++j4) mreg[j4] = float4{0, 0, 0, 0};
    }
    __syncthreads();
    #pragma unroll 1
    for (int it = 0; it < 56; ++it) {
        const float* xr = (it & 1) ? x1 : x0;
        float* xw = (it & 1) ? x0 : x1;
        if (tid < SS) {
            float sx = 0.f, sy = 0.f, sz = 0.f, sw = 0.f;
            #pragma unroll
            for (int j4 = 0; j4 < 25; ++j4) {
                float4 xv = *(const float4*)(xr + j4 * 4);   // broadcast read
                sx = fmaf(mreg[j4].x, xv.x, sx);
                sy = fmaf(mreg[j4].y, xv.y, sy);
                sz = fmaf(mreg[j4].z, xv.z, sz);
                sw = fmaf(mreg[j4].w, xv.w, sw);
            }
            xw[tid] = 0.002f + ((sx + sy) + (sz + sw));
        }
        __syncthreads();
    }
    if (tid < SS) out[(size_t)b * SS + tid] = x0[tid];       // it=55 wrote x0
}

extern "C" void kernel_launch(void* const* d_in, const int* in_sizes, int n_in,
                              void* d_out, int out_size, void* d_ws, size_t ws_size,
                              hipStream_t stream) {
    (void)in_sizes; (void)n_in; (void)out_size; (void)ws_size;
    const float* X    = (const float*)d_in[0];
    const float* Wc   = (const float*)d_in[2];
    const float* Wsim = (const float*)d_in[3];
    const float* Wrel = (const float*)d_in[4];
    const float* bmat = (const float*)d_in[5];
    float* out = (float*)d_out;

    char* ws = (char*)d_ws;
    size_t off = 0;
    float*  qbuf = (float*)(ws + off);  off += (size_t)BB * SS * SS * 4;   // 20.48 MB
    float*  drep = (float*)(ws + off);  off += (size_t)BB * HH * 4;        // 1.57 MB
    float*  tmat = (float*)(ws + off);  off += (size_t)BB * HH * 4;        // 1.57 MB
    float*  avec = (float*)(ws + off);  off += (size_t)BB * SS * 4;        // 0.20 MB
    __bf16* Wth  = (__bf16*)(ws + off); off += (size_t)HH * HH * 2;        // 1.18 MB
    __bf16* Wtl  = (__bf16*)(ws + off); off += (size_t)HH * HH * 2;        // 1.18 MB
    __bf16* Xh   = (__bf16*)(ws + off); off += (size_t)CB * SS * HH * 2;   // 19.66 MB
    __bf16* Xl   = (__bf16*)(ws + off); off += (size_t)CB * SS * HH * 2;
    __bf16* Yh   = (__bf16*)(ws + off); off += (size_t)CB * SS * HH * 2;
    __bf16* Yl   = (__bf16*)(ws + off); off += (size_t)CB * SS * HH * 2;   // total ~105 MB

    k_drep<<<BB, 256, 0, stream>>>(X, drep);
    k_gemm_nt<<<dim3(HH / 64, BB / 64), 256, 0, stream>>>(drep, Wrel, tmat, HH, HH);
    k_contrel<<<BB, 256, 0, stream>>>(X, Wc, tmat, bmat, avec);
    k_splitw<<<dim3(HH / 32, HH / 32), 256, 0, stream>>>(Wsim, Wth, Wtl);

    const int n4 = CB * SS * HH / 4;
    for (int c = 0; c < BB; c += CB) {
        k_split<<<(n4 + 255) / 256, 256, 0, stream>>>(X + (size_t)c * SS * HH, Xh, Xl, n4);
        k_gemm1_mfma<<<dim3(HH / 128, CB * SS / 128), 256, 0, stream>>>(Xh, Xl, Wth, Wtl, Yh, Yl);
        k_gemm2_mfma<<<2 * CB, 256, 0, stream>>>(Yh, Yl, Xh, Xl, avec, qbuf, c);
    }
    k_solve<<<BB, 128, 0, stream>>>(qbuf, out);
}

// Round 4
// 755.311 us; speedup vs baseline: 1.9234x; 1.2407x over previous
//
#include <hip/hip_runtime.h>
#include <math.h>

#define BB 512
#define SS 100
#define HH 768

typedef __bf16 bf16x8 __attribute__((ext_vector_type(8)));
typedef __bf16 bf16x4 __attribute__((ext_vector_type(4)));
typedef float f32x4 __attribute__((ext_vector_type(4)));

__device__ __forceinline__ void gld16(const void* g, void* l) {
    __builtin_amdgcn_global_load_lds((const __attribute__((address_space(1))) char*)g,
                                     (__attribute__((address_space(3))) char*)l, 16, 0, 0);
}

// ---------------- K0: d_rep[b,h] = mean_s X[b,s,h]  (coalesced float4 col-reduce) ----------------
__global__ __launch_bounds__(256) void k_drep(const float* __restrict__ X,
                                              float* __restrict__ drep) {
    int b = blockIdx.x, g = blockIdx.y;              // g in [0,3): 64 float4-cols each
    int lane = threadIdx.x & 63, w = threadIdx.x >> 6;
    const float4* xb = (const float4*)(X + (size_t)b * SS * HH);
    int c4 = g * 64 + lane;
    float4 s = {0.f, 0.f, 0.f, 0.f};
    for (int r = w; r < SS; r += 4) {
        float4 v = xb[r * 192 + c4];
        s.x += v.x; s.y += v.y; s.z += v.z; s.w += v.w;
    }
    __shared__ float4 red[4][64];
    red[w][lane] = s;
    __syncthreads();
    if (w == 0) {
        float4 a0 = red[0][lane], a1 = red[1][lane], a2 = red[2][lane], a3 = red[3][lane];
        float4 o;
        o.x = (a0.x + a1.x + a2.x + a3.x) * (1.0f / SS);
        o.y = (a0.y + a1.y + a2.y + a3.y) * (1.0f / SS);
        o.z = (a0.z + a1.z + a2.z + a3.z) * (1.0f / SS);
        o.w = (a0.w + a1.w + a2.w + a3.w) * (1.0f / SS);
        ((float4*)(drep + (size_t)b * HH))[c4] = o;
    }
}

// ---------------- K1: t = d_rep @ W_rel^T  (fp32 NT, 64x64x16; 0.6 GFLOP) ----------------
__global__ __launch_bounds__(256) void k_gemm_nt(const float* __restrict__ A,
                                                 const float* __restrict__ Bm,
                                                 float* __restrict__ C,
                                                 int N, int K) {
    __shared__ float As[64 * 20];
    __shared__ float Bs[64 * 20];
    int tid = threadIdx.x;
    int ty = tid >> 4, tx = tid & 15;
    int m0 = blockIdx.y * 64, n0 = blockIdx.x * 64;
    int lr = tid >> 2, lc = (tid & 3) * 4;
    float acc[4][4] = {};
    for (int kt = 0; kt < K; kt += 16) {
        *(float4*)(As + lr * 20 + lc) = *(const float4*)(A + (size_t)(m0 + lr) * K + kt + lc);
        *(float4*)(Bs + lr * 20 + lc) = *(const float4*)(Bm + (size_t)(n0 + lr) * K + kt + lc);
        __syncthreads();
        #pragma unroll
        for (int k = 0; k < 16; k += 2) {
            float2 ar[4], br[4];
            #pragma unroll
            for (int ii = 0; ii < 4; ++ii) ar[ii] = *(const float2*)(As + (ty + 16 * ii) * 20 + k);
            #pragma unroll
            for (int jj = 0; jj < 4; ++jj) br[jj] = *(const float2*)(Bs + (tx + 16 * jj) * 20 + k);
            #pragma unroll
            for (int ii = 0; ii < 4; ++ii)
                #pragma unroll
                for (int jj = 0; jj < 4; ++jj)
                    acc[ii][jj] = fmaf(ar[ii].y, br[jj].y, fmaf(ar[ii].x, br[jj].x, acc[ii][jj]));
        }
        __syncthreads();
    }
    #pragma unroll
    for (int ii = 0; ii < 4; ++ii)
        #pragma unroll
        for (int jj = 0; jj < 4; ++jj)
            C[(size_t)(m0 + ty + 16 * ii) * N + n0 + tx + 16 * jj] = acc[ii][jj];
}

// ---------------- K_splitw: W(K x N) -> Wt_h/Wt_l (N x K) bf16 split ----------------
__global__ __launch_bounds__(256) void k_splitw(const float* __restrict__ W,
                                                __bf16* __restrict__ th,
                                                __bf16* __restrict__ tl) {
    __shared__ float tile[32][33];
    int bn = blockIdx.x * 32, bk = blockIdx.y * 32;
    int tx = threadIdx.x & 31, ty = threadIdx.x >> 5;
    for (int r = ty; r < 32; r += 8)
        tile[r][tx] = W[(size_t)(bk + r) * HH + bn + tx];
    __syncthreads();
    for (int r = ty; r < 32; r += 8) {
        float v = tile[tx][r];
        __bf16 hv = (__bf16)v;
        size_t idx = (size_t)(bn + r) * HH + bk + tx;
        th[idx] = hv;
        tl[idx] = (__bf16)(v - (float)hv);
    }
}

// ---------------- K_split+contrel: split X chunk to bf16 hi/lo AND a[b,i]=X[b,i]·u[b]+b00 ----------------
__global__ __launch_bounds__(512) void k_split_contrel(const float* __restrict__ X,
                                                       const float* __restrict__ Wc,
                                                       const float* __restrict__ tmat,
                                                       const float* __restrict__ bmat,
                                                       __bf16* __restrict__ Xh,
                                                       __bf16* __restrict__ Xl,
                                                       float* __restrict__ avec,
                                                       int b_off) {
    __shared__ float4 u4[192];
    int lb = blockIdx.x, half = blockIdx.y;
    int b = b_off + lb;
    int tid = threadIdx.x, lane = tid & 63, w = tid >> 6;   // 8 waves
    for (int c = tid; c < 192; c += 512) {
        float4 wc = ((const float4*)Wc)[c];
        float4 tm = ((const float4*)(tmat + (size_t)b * HH))[c];
        float4 o = {wc.x + tm.x, wc.y + tm.y, wc.z + tm.z, wc.w + tm.w};
        u4[c] = o;
    }
    __syncthreads();
    float b00 = bmat[0];
    const float4* xb = (const float4*)(X + (size_t)b * SS * HH);
    bf16x4* xh4 = (bf16x4*)(Xh + (size_t)lb * SS * HH);
    bf16x4* xl4 = (bf16x4*)(Xl + (size_t)lb * SS * HH);
    int rend = half * 50 + 50;
    for (int r = half * 50 + w; r < rend; r += 8) {
        float s = 0.f;
        #pragma unroll
        for (int cc = 0; cc < 3; ++cc) {
            int c = cc * 64 + lane;
            float4 v = xb[r * 192 + c];
            float4 uu = u4[c];
            s = fmaf(v.x, uu.x, fmaf(v.y, uu.y, fmaf(v.z, uu.z, fmaf(v.w, uu.w, s))));
            bf16x4 hv, lv;
            hv[0] = (__bf16)v.x; lv[0] = (__bf16)(v.x - (float)hv[0]);
            hv[1] = (__bf16)v.y; lv[1] = (__bf16)(v.y - (float)hv[1]);
            hv[2] = (__bf16)v.z; lv[2] = (__bf16)(v.z - (float)hv[2]);
            hv[3] = (__bf16)v.w; lv[3] = (__bf16)(v.w - (float)hv[3]);
            xh4[r * 192 + c] = hv;
            xl4[r * 192 + c] = lv;
        }
        #pragma unroll
        for (int off = 32; off > 0; off >>= 1) s += __shfl_down(s, off);
        if (lane == 0) avec[(size_t)b * SS + r] = s + b00;
    }
}

// ---------------- K3: GEMM1 MFMA  Y = X @ W  (NT on split-bf16, 128x128, BK=32) ----------------
__global__ __launch_bounds__(256) void k_gemm1_mfma(const __bf16* __restrict__ Ah_g,
                                                    const __bf16* __restrict__ Al_g,
                                                    const __bf16* __restrict__ Bh_g,
                                                    const __bf16* __restrict__ Bl_g,
                                                    __bf16* __restrict__ Yh,
                                                    __bf16* __restrict__ Yl) {
    __shared__ __align__(16) __bf16 lds[4 * 4096];
    __bf16* As_h = lds;
    __bf16* As_l = lds + 4096;
    __bf16* Bs_h = lds + 8192;
    __bf16* Bs_l = lds + 12288;
    const int tid = threadIdx.x;
    const int wave = tid >> 6, lane = tid & 63;
    const int wy = wave >> 1, wx = wave & 1;
    const size_t m0 = (size_t)blockIdx.y * 128;
    const int n0 = blockIdx.x * 128;

    const int srow = wave * 32 + (lane >> 2);
    const int scol = (lane & 3) * 8;
    const int lds_base = wave * 1024;

    const int arow = wy * 64 + (lane & 15);
    const int brow = wx * 64 + (lane & 15);
    const int koff = (lane >> 4) * 8;

    f32x4 acc[4][4] = {};
    for (int kt = 0; kt < HH; kt += 32) {
        const size_t ga0 = (m0 + srow) * HH + kt + scol;
        const size_t ga1 = ga0 + (size_t)16 * HH;
        const size_t gb0 = (size_t)(n0 + srow) * HH + kt + scol;
        const size_t gb1 = gb0 + (size_t)16 * HH;
        gld16(Ah_g + ga0, As_h + lds_base);
        gld16(Ah_g + ga1, As_h + lds_base + 512);
        gld16(Al_g + ga0, As_l + lds_base);
        gld16(Al_g + ga1, As_l + lds_base + 512);
        gld16(Bh_g + gb0, Bs_h + lds_base);
        gld16(Bh_g + gb1, Bs_h + lds_base + 512);
        gld16(Bl_g + gb0, Bs_l + lds_base);
        gld16(Bl_g + gb1, Bs_l + lds_base + 512);
        __syncthreads();
        bf16x8 fah[4], fal[4], fbh[4], fbl[4];
        #pragma unroll
        for (int t = 0; t < 4; ++t) {
            fah[t] = *(const bf16x8*)(As_h + (arow + t * 16) * 32 + koff);
            fal[t] = *(const bf16x8*)(As_l + (arow + t * 16) * 32 + koff);
            fbh[t] = *(const bf16x8*)(Bs_h + (brow + t * 16) * 32 + koff);
            fbl[t] = *(const bf16x8*)(Bs_l + (brow + t * 16) * 32 + koff);
        }
        #pragma unroll
        for (int ti = 0; ti < 4; ++ti)
            #pragma unroll
            for (int tj = 0; tj < 4; ++tj) {
                acc[ti][tj] = __builtin_amdgcn_mfma_f32_16x16x32_bf16(fal[ti], fbh[tj], acc[ti][tj], 0, 0, 0);
                acc[ti][tj] = __builtin_amdgcn_mfma_f32_16x16x32_bf16(fah[ti], fbl[tj], acc[ti][tj], 0, 0, 0);
                acc[ti][tj] = __builtin_amdgcn_mfma_f32_16x16x32_bf16(fah[ti], fbh[tj], acc[ti][tj], 0, 0, 0);
            }
        __syncthreads();
    }
    #pragma unroll
    for (int ti = 0; ti < 4; ++ti) {
        int row0 = wy * 64 + ti * 16 + (lane >> 4) * 4;
        #pragma unroll
        for (int tj = 0; tj < 4; ++tj) {
            int col = n0 + wx * 64 + tj * 16 + (lane & 15);
            #pragma unroll
            for (int r = 0; r < 4; ++r) {
                float v = acc[ti][tj][r];
                __bf16 hv = (__bf16)v;
                size_t idx = (m0 + row0 + r) * HH + col;
                Yh[idx] = hv;
                Yl[idx] = (__bf16)(v - (float)hv);
            }
        }
    }
}

// ---------------- K4: GEMM2 MFMA  q[b] = sigmoid(Y[b] @ X[b]^T + a[b,i]) ----------------
__global__ __launch_bounds__(256) void k_gemm2_mfma(const __bf16* __restrict__ Yh,
                                                    const __bf16* __restrict__ Yl,
                                                    const __bf16* __restrict__ Xh,
                                                    const __bf16* __restrict__ Xl,
                                                    const float* __restrict__ avec,
                                                    float* __restrict__ q, int b_off) {
    __shared__ __align__(16) __bf16 lds[12288];
    __bf16* As_h = lds;
    __bf16* As_l = lds + 2048;
    __bf16* Bs_h = lds + 4096;
    __bf16* Bs_l = lds + 8192;
    const int bl = blockIdx.x >> 1;
    const int rh = (blockIdx.x & 1) * 64;
    const int b = b_off + bl;
    const __bf16* Ah_g = Yh + (size_t)bl * SS * HH;
    const __bf16* Al_g = Yl + (size_t)bl * SS * HH;
    const __bf16* Bh_g = Xh + (size_t)bl * SS * HH;
    const __bf16* Bl_g = Xl + (size_t)bl * SS * HH;
    const int tid = threadIdx.x;
    const int wave = tid >> 6, lane = tid & 63;
    const int wy = wave >> 1, wx = wave & 1;

    int ar_ = rh + (tid >> 2); if (ar_ >= SS) ar_ = SS - 1;
    const int scol = (lane & 3) * 8;
    const int a_base = wave * 512;
    const int sbrow = wave * 32 + (lane >> 2);
    const int b_base = wave * 1024;
    const int br0 = sbrow < SS ? sbrow : SS - 1;
    const int br1 = (sbrow + 16) < SS ? (sbrow + 16) : SS - 1;

    const int arow = wy * 32 + (lane & 15);
    const int brow = wx * 64 + (lane & 15);
    const int koff = (lane >> 4) * 8;

    f32x4 acc[2][4] = {};
    for (int kt = 0; kt < HH; kt += 32) {
        const size_t ga  = (size_t)ar_ * HH + kt + scol;
        const size_t gb0 = (size_t)br0 * HH + kt + scol;
        const size_t gb1 = (size_t)br1 * HH + kt + scol;
        gld16(Ah_g + ga,  As_h + a_base);
        gld16(Al_g + ga,  As_l + a_base);
        gld16(Bh_g + gb0, Bs_h + b_base);
        gld16(Bh_g + gb1, Bs_h + b_base + 512);
        gld16(Bl_g + gb0, Bs_l + b_base);
        gld16(Bl_g + gb1, Bs_l + b_base + 512);
        __syncthreads();
        bf16x8 fah[2], fal[2], fbh[4], fbl[4];
        #pragma unroll
        for (int t = 0; t < 2; ++t) {
            fah[t] = *(const bf16x8*)(As_h + (arow + t * 16) * 32 + koff);
            fal[t] = *(const bf16x8*)(As_l + (arow + t * 16) * 32 + koff);
        }
        #pragma unroll
        for (int t = 0; t < 4; ++t) {
            fbh[t] = *(const bf16x8*)(Bs_h + (brow + t * 16) * 32 + koff);
            fbl[t] = *(const bf16x8*)(Bs_l + (brow + t * 16) * 32 + koff);
        }
        #pragma unroll
        for (int ti = 0; ti < 2; ++ti)
            #pragma unroll
            for (int tj = 0; tj < 4; ++tj) {
                acc[ti][tj] = __builtin_amdgcn_mfma_f32_16x16x32_bf16(fal[ti], fbh[tj], acc[ti][tj], 0, 0, 0);
                acc[ti][tj] = __builtin_amdgcn_mfma_f32_16x16x32_bf16(fah[ti], fbl[tj], acc[ti][tj], 0, 0, 0);
                acc[ti][tj] = __builtin_amdgcn_mfma_f32_16x16x32_bf16(fah[ti], fbh[tj], acc[ti][tj], 0, 0, 0);
            }
        __syncthreads();
    }
    float* qb = q + (size_t)b * SS * SS;
    const float* av = avec + (size_t)b * SS;
    #pragma unroll
    for (int ti = 0; ti < 2; ++ti) {
        int i0 = rh + wy * 32 + ti * 16 + (lane >> 4) * 4;
        if (i0 >= SS) continue;
        #pragma unroll
        for (int tj = 0; tj < 4; ++tj) {
            int j = wx * 64 + tj * 16 + (lane & 15);
            if (j >= SS) continue;
            #pragma unroll
            for (int r = 0; r < 4; ++r) {
                int i = i0 + r;
                if (i >= SS) continue;
                float v = acc[ti][tj][r] + av[i];
                qb[(size_t)i * SS + j] = 1.0f / (1.0f + __expf(-v));
            }
        }
    }
}

// ---------------- K5: colsum + fixed-point solve, M held in registers ----------------
__global__ __launch_bounds__(128) void k_solve(const float* __restrict__ q,
                                               float* __restrict__ out) {
    __shared__ __align__(16) float m[SS * SS];
    __shared__ __align__(16) float csinv[SS];
    __shared__ __align__(16) float x0[SS], x1[SS];
    int b = blockIdx.x, tid = threadIdx.x;
    const float* qb = q + (size_t)b * SS * SS;
    for (int e4 = tid; e4 < SS * SS / 4; e4 += 128)
        *(float4*)(m + e4 * 4) = *(const float4*)(qb + (size_t)e4 * 4);
    __syncthreads();
    if (tid < SS) {
        float s = 0.f;
        for (int i = 0; i < SS; ++i) s += m[i * SS + tid];
        csinv[tid] = 0.8f / s;
        x0[tid] = 1.0f / SS;
    }
    __syncthreads();
    float4 mreg[25];
    if (tid < SS) {
        #pragma unroll
        for (int j4 = 0; j4 < 25; ++j4) {
            float4 mv = *(const float4*)(m + tid * SS + j4 * 4);
            float4 cv = *(const float4*)(csinv + j4 * 4);
            mreg[j4].x = mv.x * cv.x;
            mreg[j4].y = mv.y * cv.y;
            mreg[j4].z = mv.z * cv.z;
            mreg[j4].w = mv.w * cv.w;
        }
    } else {
        #pragma unroll
        for (int j4 = 0; j4 < 25; ++j4) mreg[j4] = float4{0, 0, 0, 0};
    }
    __syncthreads();
    #pragma unroll 1
    for (int it = 0; it < 56; ++it) {
        const float* xr = (it & 1) ? x1 : x0;
        float* xw = (it & 1) ? x0 : x1;
        if (tid < SS) {
            float sx = 0.f, sy = 0.f, sz = 0.f, sw = 0.f;
            #pragma unroll
            for (int j4 = 0; j4 < 25; ++j4) {
                float4 xv = *(const float4*)(xr + j4 * 4);
                sx = fmaf(mreg[j4].x, xv.x, sx);
                sy = fmaf(mreg[j4].y, xv.y, sy);
                sz = fmaf(mreg[j4].z, xv.z, sz);
                sw = fmaf(mreg[j4].w, xv.w, sw);
            }
            xw[tid] = 0.002f + ((sx + sy) + (sz + sw));
        }
        __syncthreads();
    }
    if (tid < SS) out[(size_t)b * SS + tid] = x0[tid];
}

extern "C" void kernel_launch(void* const* d_in, const int* in_sizes, int n_in,
                              void* d_out, int out_size, void* d_ws, size_t ws_size,
                              hipStream_t stream) {
    (void)in_sizes; (void)n_in; (void)out_size;
    const float* X    = (const float*)d_in[0];
    const float* Wc   = (const float*)d_in[2];
    const float* Wsim = (const float*)d_in[3];
    const float* Wrel = (const float*)d_in[4];
    const float* bmat = (const float*)d_in[5];
    float* out = (float*)d_out;

    char* ws = (char*)d_ws;
    size_t off = 0;
    float*  qbuf = (float*)(ws + off);  off += (size_t)BB * SS * SS * 4;   // 20.48 MB
    float*  drep = (float*)(ws + off);  off += (size_t)BB * HH * 4;        // 1.57 MB
    float*  tmat = (float*)(ws + off);  off += (size_t)BB * HH * 4;        // 1.57 MB
    float*  avec = (float*)(ws + off);  off += (size_t)BB * SS * 4;        // 0.20 MB
    __bf16* Wth  = (__bf16*)(ws + off); off += (size_t)HH * HH * 2;        // 1.18 MB
    __bf16* Wtl  = (__bf16*)(ws + off); off += (size_t)HH * HH * 2;        // 1.18 MB

    // dynamic chunk: CB=512 needs ~341 MB total, 256 ~183 MB, 128 ~105 MB
    int CB = 512;
    while (CB > 128 && off + 4 * (size_t)CB * SS * HH * 2 > ws_size) CB >>= 1;
    size_t xsz = (size_t)CB * SS * HH * 2;
    __bf16* Xh = (__bf16*)(ws + off); off += xsz;
    __bf16* Xl = (__bf16*)(ws + off); off += xsz;
    __bf16* Yh = (__bf16*)(ws + off); off += xsz;
    __bf16* Yl = (__bf16*)(ws + off); off += xsz;

    k_drep<<<dim3(BB, 3), 256, 0, stream>>>(X, drep);
    k_gemm_nt<<<dim3(HH / 64, BB / 64), 256, 0, stream>>>(drep, Wrel, tmat, HH, HH);
    k_splitw<<<dim3(HH / 32, HH / 32), 256, 0, stream>>>(Wsim, Wth, Wtl);

    for (int c = 0; c < BB; c += CB) {
        k_split_contrel<<<dim3(CB, 2), 512, 0, stream>>>(X + (size_t)c * SS * HH, Wc, tmat, bmat, Xh, Xl, avec, c);
        k_gemm1_mfma<<<dim3(HH / 128, CB * SS / 128), 256, 0, stream>>>(Xh, Xl, Wth, Wtl, Yh, Yl);
        k_gemm2_mfma<<<2 * CB, 256, 0, stream>>>(Yh, Yl, Xh, Xl, avec, qbuf, c);
    }
    k_solve<<<BB, 128, 0, stream>>>(qbuf, out);
}

// Round 5
// 732.412 us; speedup vs baseline: 1.9835x; 1.0313x over previous
//
#include <hip/hip_runtime.h>
#include <math.h>

#define BB 512
#define SS 100
#define HH 768

typedef __bf16 bf16x8 __attribute__((ext_vector_type(8)));
typedef __bf16 bf16x4 __attribute__((ext_vector_type(4)));
typedef float f32x4 __attribute__((ext_vector_type(4)));
typedef float f32x16 __attribute__((ext_vector_type(16)));

__device__ __forceinline__ void gld16(const void* g, void* l) {
    __builtin_amdgcn_global_load_lds((const __attribute__((address_space(1))) char*)g,
                                     (__attribute__((address_space(3))) char*)l, 16, 0, 0);
}

// ---------------- K0: d_rep[b,h] = mean_s X[b,s,h]  (coalesced float4 col-reduce) ----------------
__global__ __launch_bounds__(256) void k_drep(const float* __restrict__ X,
                                              float* __restrict__ drep) {
    int b = blockIdx.x, g = blockIdx.y;
    int lane = threadIdx.x & 63, w = threadIdx.x >> 6;
    const float4* xb = (const float4*)(X + (size_t)b * SS * HH);
    int c4 = g * 64 + lane;
    float4 s = {0.f, 0.f, 0.f, 0.f};
    for (int r = w; r < SS; r += 4) {
        float4 v = xb[r * 192 + c4];
        s.x += v.x; s.y += v.y; s.z += v.z; s.w += v.w;
    }
    __shared__ float4 red[4][64];
    red[w][lane] = s;
    __syncthreads();
    if (w == 0) {
        float4 a0 = red[0][lane], a1 = red[1][lane], a2 = red[2][lane], a3 = red[3][lane];
        float4 o;
        o.x = (a0.x + a1.x + a2.x + a3.x) * (1.0f / SS);
        o.y = (a0.y + a1.y + a2.y + a3.y) * (1.0f / SS);
        o.z = (a0.z + a1.z + a2.z + a3.z) * (1.0f / SS);
        o.w = (a0.w + a1.w + a2.w + a3.w) * (1.0f / SS);
        ((float4*)(drep + (size_t)b * HH))[c4] = o;
    }
}

// ---------------- K1: t = d_rep @ W_rel^T  (fp32 NT, 64x64x16; 0.6 GFLOP) ----------------
__global__ __launch_bounds__(256) void k_gemm_nt(const float* __restrict__ A,
                                                 const float* __restrict__ Bm,
                                                 float* __restrict__ C,
                                                 int N, int K) {
    __shared__ float As[64 * 20];
    __shared__ float Bs[64 * 20];
    int tid = threadIdx.x;
    int ty = tid >> 4, tx = tid & 15;
    int m0 = blockIdx.y * 64, n0 = blockIdx.x * 64;
    int lr = tid >> 2, lc = (tid & 3) * 4;
    float acc[4][4] = {};
    for (int kt = 0; kt < K; kt += 16) {
        *(float4*)(As + lr * 20 + lc) = *(const float4*)(A + (size_t)(m0 + lr) * K + kt + lc);
        *(float4*)(Bs + lr * 20 + lc) = *(const float4*)(Bm + (size_t)(n0 + lr) * K + kt + lc);
        __syncthreads();
        #pragma unroll
        for (int k = 0; k < 16; k += 2) {
            float2 ar[4], br[4];
            #pragma unroll
            for (int ii = 0; ii < 4; ++ii) ar[ii] = *(const float2*)(As + (ty + 16 * ii) * 20 + k);
            #pragma unroll
            for (int jj = 0; jj < 4; ++jj) br[jj] = *(const float2*)(Bs + (tx + 16 * jj) * 20 + k);
            #pragma unroll
            for (int ii = 0; ii < 4; ++ii)
                #pragma unroll
                for (int jj = 0; jj < 4; ++jj)
                    acc[ii][jj] = fmaf(ar[ii].y, br[jj].y, fmaf(ar[ii].x, br[jj].x, acc[ii][jj]));
        }
        __syncthreads();
    }
    #pragma unroll
    for (int ii = 0; ii < 4; ++ii)
        #pragma unroll
        for (int jj = 0; jj < 4; ++jj)
            C[(size_t)(m0 + ty + 16 * ii) * N + n0 + tx + 16 * jj] = acc[ii][jj];
}

// ---------------- K_splitw: W(K x N) -> Wt_h/Wt_l (N x K) bf16 split ----------------
__global__ __launch_bounds__(256) void k_splitw(const float* __restrict__ W,
                                                __bf16* __restrict__ th,
                                                __bf16* __restrict__ tl) {
    __shared__ float tile[32][33];
    int bn = blockIdx.x * 32, bk = blockIdx.y * 32;
    int tx = threadIdx.x & 31, ty = threadIdx.x >> 5;
    for (int r = ty; r < 32; r += 8)
        tile[r][tx] = W[(size_t)(bk + r) * HH + bn + tx];
    __syncthreads();
    for (int r = ty; r < 32; r += 8) {
        float v = tile[tx][r];
        __bf16 hv = (__bf16)v;
        size_t idx = (size_t)(bn + r) * HH + bk + tx;
        th[idx] = hv;
        tl[idx] = (__bf16)(v - (float)hv);
    }
}

// ---------------- K_split+contrel: split X chunk to bf16 hi/lo AND a[b,i]=X[b,i]·u[b]+b00 ----------------
__global__ __launch_bounds__(512) void k_split_contrel(const float* __restrict__ X,
                                                       const float* __restrict__ Wc,
                                                       const float* __restrict__ tmat,
                                                       const float* __restrict__ bmat,
                                                       __bf16* __restrict__ Xh,
                                                       __bf16* __restrict__ Xl,
                                                       float* __restrict__ avec,
                                                       int b_off) {
    __shared__ float4 u4[192];
    int lb = blockIdx.x, half = blockIdx.y;
    int b = b_off + lb;
    int tid = threadIdx.x, lane = tid & 63, w = tid >> 6;
    for (int c = tid; c < 192; c += 512) {
        float4 wc = ((const float4*)Wc)[c];
        float4 tm = ((const float4*)(tmat + (size_t)b * HH))[c];
        float4 o = {wc.x + tm.x, wc.y + tm.y, wc.z + tm.z, wc.w + tm.w};
        u4[c] = o;
    }
    __syncthreads();
    float b00 = bmat[0];
    const float4* xb = (const float4*)(X + (size_t)b * SS * HH);
    bf16x4* xh4 = (bf16x4*)(Xh + (size_t)lb * SS * HH);
    bf16x4* xl4 = (bf16x4*)(Xl + (size_t)lb * SS * HH);
    int rend = half * 50 + 50;
    for (int r = half * 50 + w; r < rend; r += 8) {
        float s = 0.f;
        #pragma unroll
        for (int cc = 0; cc < 3; ++cc) {
            int c = cc * 64 + lane;
            float4 v = xb[r * 192 + c];
            float4 uu = u4[c];
            s = fmaf(v.x, uu.x, fmaf(v.y, uu.y, fmaf(v.z, uu.z, fmaf(v.w, uu.w, s))));
            bf16x4 hv, lv;
            hv[0] = (__bf16)v.x; lv[0] = (__bf16)(v.x - (float)hv[0]);
            hv[1] = (__bf16)v.y; lv[1] = (__bf16)(v.y - (float)hv[1]);
            hv[2] = (__bf16)v.z; lv[2] = (__bf16)(v.z - (float)hv[2]);
            hv[3] = (__bf16)v.w; lv[3] = (__bf16)(v.w - (float)hv[3]);
            xh4[r * 192 + c] = hv;
            xl4[r * 192 + c] = lv;
        }
        #pragma unroll
        for (int off = 32; off > 0; off >>= 1) s += __shfl_down(s, off);
        if (lane == 0) avec[(size_t)b * SS + r] = s + b00;
    }
}

// ---------------- K3: GEMM1 MFMA 32x32x16  Y = X @ W  (NT, split-bf16, 128x128, BK=32) ----------------
__global__ __launch_bounds__(256) void k_gemm1_mfma(const __bf16* __restrict__ Ah_g,
                                                    const __bf16* __restrict__ Al_g,
                                                    const __bf16* __restrict__ Bh_g,
                                                    const __bf16* __restrict__ Bl_g,
                                                    __bf16* __restrict__ Yh,
                                                    __bf16* __restrict__ Yl) {
    __shared__ __align__(16) __bf16 lds[4 * 4096];
    __bf16* As_h = lds;
    __bf16* As_l = lds + 4096;
    __bf16* Bs_h = lds + 8192;
    __bf16* Bs_l = lds + 12288;
    const int tid = threadIdx.x;
    const int wave = tid >> 6, lane = tid & 63;
    const int wy = wave >> 1, wx = wave & 1;
    const size_t m0 = (size_t)blockIdx.y * 128;
    const int n0 = blockIdx.x * 128;

    const int srow = wave * 32 + (lane >> 2);
    const int scol = (lane & 3) * 8;
    const int lds_base = wave * 1024;

    const int arow = wy * 64 + (lane & 31);   // + t*32
    const int brow = wx * 64 + (lane & 31);
    const int koct = (lane >> 5) * 8;         // + kh*16

    f32x16 acc[2][2] = {};
    for (int kt = 0; kt < HH; kt += 32) {
        const size_t ga0 = (m0 + srow) * HH + kt + scol;
        const size_t ga1 = ga0 + (size_t)16 * HH;
        const size_t gb0 = (size_t)(n0 + srow) * HH + kt + scol;
        const size_t gb1 = gb0 + (size_t)16 * HH;
        gld16(Ah_g + ga0, As_h + lds_base);
        gld16(Ah_g + ga1, As_h + lds_base + 512);
        gld16(Al_g + ga0, As_l + lds_base);
        gld16(Al_g + ga1, As_l + lds_base + 512);
        gld16(Bh_g + gb0, Bs_h + lds_base);
        gld16(Bh_g + gb1, Bs_h + lds_base + 512);
        gld16(Bl_g + gb0, Bs_l + lds_base);
        gld16(Bl_g + gb1, Bs_l + lds_base + 512);
        __syncthreads();
        #pragma unroll
        for (int kh = 0; kh < 2; ++kh) {
            const int ko = kh * 16 + koct;
            bf16x8 fah[2], fal[2], fbh[2], fbl[2];
            #pragma unroll
            for (int t = 0; t < 2; ++t) {
                fah[t] = *(const bf16x8*)(As_h + (arow + t * 32) * 32 + ko);
                fal[t] = *(const bf16x8*)(As_l + (arow + t * 32) * 32 + ko);
                fbh[t] = *(const bf16x8*)(Bs_h + (brow + t * 32) * 32 + ko);
                fbl[t] = *(const bf16x8*)(Bs_l + (brow + t * 32) * 32 + ko);
            }
            #pragma unroll
            for (int ti = 0; ti < 2; ++ti)
                #pragma unroll
                for (int tj = 0; tj < 2; ++tj) {
                    acc[ti][tj] = __builtin_amdgcn_mfma_f32_32x32x16_bf16(fal[ti], fbh[tj], acc[ti][tj], 0, 0, 0);
                    acc[ti][tj] = __builtin_amdgcn_mfma_f32_32x32x16_bf16(fah[ti], fbl[tj], acc[ti][tj], 0, 0, 0);
                    acc[ti][tj] = __builtin_amdgcn_mfma_f32_32x32x16_bf16(fah[ti], fbh[tj], acc[ti][tj], 0, 0, 0);
                }
        }
        __syncthreads();
    }
    // 32x32 C/D: col = lane&31, row = (reg&3) + 8*(reg>>2) + 4*(lane>>5)  [m74/m101]
    const int rbase = 4 * (lane >> 5);
    const int colb = lane & 31;
    #pragma unroll
    for (int ti = 0; ti < 2; ++ti) {
        #pragma unroll
        for (int tj = 0; tj < 2; ++tj) {
            int col = n0 + wx * 64 + tj * 32 + colb;
            #pragma unroll
            for (int r = 0; r < 16; ++r) {
                int row = wy * 64 + ti * 32 + (r & 3) + 8 * (r >> 2) + rbase;
                float v = acc[ti][tj][r];
                __bf16 hv = (__bf16)v;
                size_t idx = (m0 + row) * HH + col;
                Yh[idx] = hv;
                Yl[idx] = (__bf16)(v - (float)hv);
            }
        }
    }
}

// ---------------- K4: GEMM2 MFMA 32x32x16  q[b] = sigmoid(Y[b] @ X[b]^T + a[b,i]) ----------------
// One 128x128 block per batch (staging rows clamped to 99; outputs guarded).
__global__ __launch_bounds__(256) void k_gemm2_mfma(const __bf16* __restrict__ Yh,
                                                    const __bf16* __restrict__ Yl,
                                                    const __bf16* __restrict__ Xh,
                                                    const __bf16* __restrict__ Xl,
                                                    const float* __restrict__ avec,
                                                    float* __restrict__ q, int b_off) {
    __shared__ __align__(16) __bf16 lds[4 * 4096];
    __shared__ float av_s[SS];
    __bf16* As_h = lds;
    __bf16* As_l = lds + 4096;
    __bf16* Bs_h = lds + 8192;
    __bf16* Bs_l = lds + 12288;
    const int bl = blockIdx.x;
    const int b = b_off + bl;
    const __bf16* Ah_g = Yh + (size_t)bl * SS * HH;
    const __bf16* Al_g = Yl + (size_t)bl * SS * HH;
    const __bf16* Bh_g = Xh + (size_t)bl * SS * HH;
    const __bf16* Bl_g = Xl + (size_t)bl * SS * HH;
    const int tid = threadIdx.x;
    const int wave = tid >> 6, lane = tid & 63;
    const int wy = wave >> 1, wx = wave & 1;
    if (tid < SS) av_s[tid] = avec[(size_t)b * SS + tid];

    const int srow_raw = wave * 32 + (lane >> 2);
    const int scol = (lane & 3) * 8;
    const int lds_base = wave * 1024;
    const int r0 = srow_raw < SS ? srow_raw : SS - 1;
    const int r1 = (srow_raw + 16) < SS ? (srow_raw + 16) : SS - 1;

    const int arow = wy * 64 + (lane & 31);
    const int brow = wx * 64 + (lane & 31);
    const int koct = (lane >> 5) * 8;

    f32x16 acc[2][2] = {};
    for (int kt = 0; kt < HH; kt += 32) {
        const size_t ga0 = (size_t)r0 * HH + kt + scol;
        const size_t ga1 = (size_t)r1 * HH + kt + scol;
        gld16(Ah_g + ga0, As_h + lds_base);
        gld16(Ah_g + ga1, As_h + lds_base + 512);
        gld16(Al_g + ga0, As_l + lds_base);
        gld16(Al_g + ga1, As_l + lds_base + 512);
        gld16(Bh_g + ga0, Bs_h + lds_base);
        gld16(Bh_g + ga1, Bs_h + lds_base + 512);
        gld16(Bl_g + ga0, Bs_l + lds_base);
        gld16(Bl_g + ga1, Bs_l + lds_base + 512);
        __syncthreads();
        #pragma unroll
        for (int kh = 0; kh < 2; ++kh) {
            const int ko = kh * 16 + koct;
            bf16x8 fah[2], fal[2], fbh[2], fbl[2];
            #pragma unroll
            for (int t = 0; t < 2; ++t) {
                fah[t] = *(const bf16x8*)(As_h + (arow + t * 32) * 32 + ko);
                fal[t] = *(const bf16x8*)(As_l + (arow + t * 32) * 32 + ko);
                fbh[t] = *(const bf16x8*)(Bs_h + (brow + t * 32) * 32 + ko);
                fbl[t] = *(const bf16x8*)(Bs_l + (brow + t * 32) * 32 + ko);
            }
            #pragma unroll
            for (int ti = 0; ti < 2; ++ti)
                #pragma unroll
                for (int tj = 0; tj < 2; ++tj) {
                    acc[ti][tj] = __builtin_amdgcn_mfma_f32_32x32x16_bf16(fal[ti], fbh[tj], acc[ti][tj], 0, 0, 0);
                    acc[ti][tj] = __builtin_amdgcn_mfma_f32_32x32x16_bf16(fah[ti], fbl[tj], acc[ti][tj], 0, 0, 0);
                    acc[ti][tj] = __builtin_amdgcn_mfma_f32_32x32x16_bf16(fah[ti], fbh[tj], acc[ti][tj], 0, 0, 0);
                }
        }
        __syncthreads();
    }
    float* qb = q + (size_t)b * SS * SS;
    const int rbase = 4 * (lane >> 5);
    const int colb = lane & 31;
    #pragma unroll
    for (int ti = 0; ti < 2; ++ti) {
        #pragma unroll
        for (int tj = 0; tj < 2; ++tj) {
            int j = wx * 64 + tj * 32 + colb;
            if (j >= SS) continue;
            #pragma unroll
            for (int r = 0; r < 16; ++r) {
                int i = wy * 64 + ti * 32 + (r & 3) + 8 * (r >> 2) + rbase;
                if (i >= SS) continue;
                float v = acc[ti][tj][r] + av_s[i];
                qb[(size_t)i * SS + j] = 1.0f / (1.0f + __expf(-v));
            }
        }
    }
}

// ---------------- K5: colsum + fixed-point solve, M held in registers ----------------
__global__ __launch_bounds__(128) void k_solve(const float* __restrict__ q,
                                               float* __restrict__ out) {
    __shared__ __align__(16) float m[SS * SS];
    __shared__ __align__(16) float csinv[SS];
    __shared__ __align__(16) float x0[SS], x1[SS];
    int b = blockIdx.x, tid = threadIdx.x;
    const float* qb = q + (size_t)b * SS * SS;
    for (int e4 = tid; e4 < SS * SS / 4; e4 += 128)
        *(float4*)(m + e4 * 4) = *(const float4*)(qb + (size_t)e4 * 4);
    __syncthreads();
    if (tid < SS) {
        float s = 0.f;
        for (int i = 0; i < SS; ++i) s += m[i * SS + tid];
        csinv[tid] = 0.8f / s;
        x0[tid] = 1.0f / SS;
    }
    __syncthreads();
    float4 mreg[25];
    if (tid < SS) {
        #pragma unroll
        for (int j4 = 0; j4 < 25; ++j4) {
            float4 mv = *(const float4*)(m + tid * SS + j4 * 4);
            float4 cv = *(const float4*)(csinv + j4 * 4);
            mreg[j4].x = mv.x * cv.x;
            mreg[j4].y = mv.y * cv.y;
            mreg[j4].z = mv.z * cv.z;
            mreg[j4].w = mv.w * cv.w;
        }
    } else {
        #pragma unroll
        for (int j4 = 0; j4 < 25; ++j4) mreg[j4] = float4{0, 0, 0, 0};
    }
    __syncthreads();
    #pragma unroll 1
    for (int it = 0; it < 56; ++it) {
        const float* xr = (it & 1) ? x1 : x0;
        float* xw = (it & 1) ? x0 : x1;
        if (tid < SS) {
            float sx = 0.f, sy = 0.f, sz = 0.f, sw = 0.f;
            #pragma unroll
            for (int j4 = 0; j4 < 25; ++j4) {
                float4 xv = *(const float4*)(xr + j4 * 4);
                sx = fmaf(mreg[j4].x, xv.x, sx);
                sy = fmaf(mreg[j4].y, xv.y, sy);
                sz = fmaf(mreg[j4].z, xv.z, sz);
                sw = fmaf(mreg[j4].w, xv.w, sw);
            }
            xw[tid] = 0.002f + ((sx + sy) + (sz + sw));
        }
        __syncthreads();
    }
    if (tid < SS) out[(size_t)b * SS + tid] = x0[tid];
}

extern "C" void kernel_launch(void* const* d_in, const int* in_sizes, int n_in,
                              void* d_out, int out_size, void* d_ws, size_t ws_size,
                              hipStream_t stream) {
    (void)in_sizes; (void)n_in; (void)out_size;
    const float* X    = (const float*)d_in[0];
    const float* Wc   = (const float*)d_in[2];
    const float* Wsim = (const float*)d_in[3];
    const float* Wrel = (const float*)d_in[4];
    const float* bmat = (const float*)d_in[5];
    float* out = (float*)d_out;

    char* ws = (char*)d_ws;
    size_t off = 0;
    float*  qbuf = (float*)(ws + off);  off += (size_t)BB * SS * SS * 4;
    float*  drep = (float*)(ws + off);  off += (size_t)BB * HH * 4;
    float*  tmat = (float*)(ws + off);  off += (size_t)BB * HH * 4;
    float*  avec = (float*)(ws + off);  off += (size_t)BB * SS * 4;
    __bf16* Wth  = (__bf16*)(ws + off); off += (size_t)HH * HH * 2;
    __bf16* Wtl  = (__bf16*)(ws + off); off += (size_t)HH * HH * 2;

    int CB = 512;
    while (CB > 128 && off + 4 * (size_t)CB * SS * HH * 2 > ws_size) CB >>= 1;
    size_t xsz = (size_t)CB * SS * HH * 2;
    __bf16* Xh = (__bf16*)(ws + off); off += xsz;
    __bf16* Xl = (__bf16*)(ws + off); off += xsz;
    __bf16* Yh = (__bf16*)(ws + off); off += xsz;
    __bf16* Yl = (__bf16*)(ws + off); off += xsz;

    k_drep<<<dim3(BB, 3), 256, 0, stream>>>(X, drep);
    k_gemm_nt<<<dim3(HH / 64, BB / 64), 256, 0, stream>>>(drep, Wrel, tmat, HH, HH);
    k_splitw<<<dim3(HH / 32, HH / 32), 256, 0, stream>>>(Wsim, Wth, Wtl);

    for (int c = 0; c < BB; c += CB) {
        k_split_contrel<<<dim3(CB, 2), 512, 0, stream>>>(X + (size_t)c * SS * HH, Wc, tmat, bmat, Xh, Xl, avec, c);
        k_gemm1_mfma<<<dim3(HH / 128, CB * SS / 128), 256, 0, stream>>>(Xh, Xl, Wth, Wtl, Yh, Yl);
        k_gemm2_mfma<<<CB, 256, 0, stream>>>(Yh, Yl, Xh, Xl, avec, qbuf, c);
    }
    k_solve<<<BB, 128, 0, stream>>>(qbuf, out);
}